// Round 14
// baseline (194.244 us; speedup 1.0000x reference)
//
#include <hip/hip_runtime.h>
#include <hip/hip_fp16.h>
#include <math.h>

#define N_NODES 40000
#define N_EDGES 640000
#define DIM     128
#define N_GRAPHS 64
#define N_CLS   100
#define EPSN    1e-12f

#define EDGE_BLOCKS ((N_EDGES + 255) / 256)   // 2500
#define NODE_BLOCKS (N_NODES / 4)             // 10000

// ---------------- CSR build + input norm (fused, independent phases) --------

__global__ void k_count_norm(const int* __restrict__ dst, int* __restrict__ counts,
                             int* __restrict__ posw,
                             const float* __restrict__ h, float* __restrict__ nrm,
                             __half2* __restrict__ nh) {
    int b = blockIdx.x;
    if (b < EDGE_BLOCKS) {
        int e = b * 256 + threadIdx.x;
        if (e < N_EDGES) posw[e] = atomicAdd(&counts[dst[e]], 1);
    } else {
        int node = ((b - EDGE_BLOCKS) << 2) + (threadIdx.x >> 6);
        int lane = threadIdx.x & 63;
        const float2* r2 = (const float2*)(h + (size_t)node * DIM);
        float2 v = r2[lane];
        float ss = v.x * v.x + v.y * v.y;
        #pragma unroll
        for (int o = 32; o; o >>= 1) ss += __shfl_xor(ss, o);
        float norm = sqrtf(ss) + EPSN;
        float inv = 1.0f / norm;
        if (lane == 0) nrm[node] = norm;
        nh[(size_t)node * 64 + lane] = __floats2half2_rn(v.x * inv, v.y * inv);
    }
}

#define SCAN_T 1024
#define SCAN_V 40   // SCAN_T * SCAN_V >= N_NODES ; N_NODES/SCAN_V = 1000 exact
__global__ void k_scan(const int* __restrict__ counts, int* __restrict__ offsets) {
    __shared__ int lds[SCAN_T];
    int t = threadIdx.x;
    int base = t * SCAN_V;
    int tsum = 0;
    int c[SCAN_V];
    if (base < N_NODES) {
        const int4* c4 = (const int4*)(counts + base);   // 160B-aligned runs
        #pragma unroll
        for (int k = 0; k < SCAN_V / 4; ++k) {
            int4 v = c4[k];
            c[4 * k] = v.x; c[4 * k + 1] = v.y; c[4 * k + 2] = v.z; c[4 * k + 3] = v.w;
            tsum += v.x + v.y + v.z + v.w;
        }
    }
    lds[t] = tsum; __syncthreads();
    int x = tsum;
    for (int off = 1; off < SCAN_T; off <<= 1) {
        int y = (t >= off) ? lds[t - off] : 0;
        __syncthreads();
        x += y;
        lds[t] = x;
        __syncthreads();
    }
    int excl = x - tsum;
    if (base < N_NODES) {
        int run = excl;
        int4* o4 = (int4*)(offsets + base);
        #pragma unroll
        for (int k = 0; k < SCAN_V / 4; ++k) {
            int4 w;
            w.x = run;
            w.y = w.x + c[4 * k];
            w.z = w.y + c[4 * k + 1];
            w.w = w.z + c[4 * k + 2];
            run = w.w + c[4 * k + 3];
            o4[k] = w;
        }
    }
    if (t == (N_NODES / SCAN_V)) offsets[N_NODES] = excl;  // total = E
}

__global__ void k_scatter(const int* __restrict__ src, const int* __restrict__ dst,
                          const int* __restrict__ offsets, const int* __restrict__ posw,
                          int* __restrict__ csr_src) {
    int e = blockIdx.x * blockDim.x + threadIdx.x;
    if (e >= N_EDGES) return;
    csr_src[offsets[dst[e]] + posw[e]] = src[e];
}

// ---------------- fused AGNN layer ----------------

// One wave per node; 4 groups of 16 lanes; lane t owns features [8t..8t+7]
// (one int4 = 8 halves). Table holds NORMALIZED rows: score = beta*(nh_s.nh_d),
// aggregation weight = w*nrm[s] applied off the dot->exp critical path.
// Edge metadata staged in LDS once per node; the full-batch loop is SOFTWARE-
// PIPELINED 1 deep: batch n+1's two row-gathers are issued before batch n's
// compute, so the ~450-900cyc L2-miss latency overlaps the ~140cyc compute.
// 16-lane dot-reduce via DPP adds (VALU pipe, no LDS round-trip).
// Softmax needs no max subtraction: scores bounded in [-beta, beta].
union H8 { int4 i4; __half2 h2[4]; };

__device__ __forceinline__ void cvt8(const H8& u, float* f) {
    #pragma unroll
    for (int k = 0; k < 4; ++k) {
        float2 v = __half22float2(u.h2[k]);
        f[2 * k]     = v.x;
        f[2 * k + 1] = v.y;
    }
}

template <int CTRL>
__device__ __forceinline__ float dpp_add(float x) {
    int v = __builtin_amdgcn_update_dpp(0, __float_as_int(x), CTRL, 0xF, 0xF, true);
    return x + __int_as_float(v);
}

__device__ __forceinline__ float red16(float p) {
    p = dpp_add<0x140>(p);   // row_mirror
    p = dpp_add<0x141>(p);   // row_half_mirror
    p = dpp_add<0x4E>(p);    // quad_perm [2,3,0,1]  (xor 2)
    p = dpp_add<0xB1>(p);    // quad_perm [1,0,3,2]  (xor 1)
    return p;
}

template <bool LAST>
__global__ void k_fused(const int4* __restrict__ nh_in,      // fp16 normalized table
                        const float* __restrict__ nrm_in,    // |h|+eps per node
                        const int* __restrict__ csr_src,
                        const int* __restrict__ offsets,
                        const float* __restrict__ betas, int layer,
                        int4* __restrict__ nh_out,            // (if !LAST)
                        float* __restrict__ nrm_out,          // (if !LAST)
                        const int* __restrict__ gid,          // (if LAST)
                        float* __restrict__ hgsum) {          // (if LAST)
    int node = (blockIdx.x * blockDim.x + threadIdx.x) >> 6;  // grid covers exactly N_NODES
    int lane = threadIdx.x & 63;
    int wid  = threadIdx.x >> 6;   // wave slot in block (0..3)
    int grp = lane >> 4;   // 0..3
    int t   = lane & 15;   // feature sublane: owns features [8t..8t+7]

    __shared__ int2 sedge[4][64];  // per-wave slot: (src idx, src nrm bits)

    int off = offsets[node];
    int deg = offsets[node + 1] - off;

    size_t nrow16 = (size_t)node * 16;
    H8 selfu; selfu.i4 = nh_in[nrow16 + t];
    float hd[8]; cvt8(selfu, hd);
    float beta = betas[layer];

    float dsum = 0.f;
    float ac[8];
    #pragma unroll
    for (int k = 0; k < 8; ++k) ac[k] = 0.f;

    if (deg > 0) {
        int dmax = min(deg, 64);
        // ---- stage edge metadata for first dmax edges ----
        if (lane < dmax) {
            int idx = csr_src[off + lane];          // coalesced
            float nr = nrm_in[idx];                 // lane-parallel gather
            sedge[wid][lane] = make_int2(idx, __float_as_int(nr));
        }
        int jb = 0;
        // ---- software-pipelined full batches: 8 edges (2 per group) ----
        if (jb + 8 <= dmax) {
            int2 ce0 = sedge[wid][grp];
            int2 ce1 = sedge[wid][4 + grp];
            H8 cu0, cu1;
            cu0.i4 = nh_in[(size_t)ce0.x * 16 + t];
            cu1.i4 = nh_in[(size_t)ce1.x * 16 + t];
            while (jb + 8 <= dmax) {
                int jn = jb + 8;
                bool more = (jn + 8 <= dmax);
                int2 ne0, ne1; H8 nu0, nu1;
                if (more) {                       // issue NEXT batch's gathers now
                    ne0 = sedge[wid][jn + grp];
                    ne1 = sedge[wid][jn + 4 + grp];
                    nu0.i4 = nh_in[(size_t)ne0.x * 16 + t];
                    nu1.i4 = nh_in[(size_t)ne1.x * 16 + t];
                }
                // ---- compute current batch ----
                float n0 = __int_as_float(ce0.y), n1 = __int_as_float(ce1.y);
                float f0[8], f1[8];
                cvt8(cu0, f0); cvt8(cu1, f1);
                float p0 = 0.f, p1 = 0.f;
                #pragma unroll
                for (int q = 0; q < 8; ++q) { p0 += f0[q] * hd[q]; p1 += f1[q] * hd[q]; }
                p0 = red16(p0);
                p1 = red16(p1);
                float w0 = __expf(beta * p0), w1 = __expf(beta * p1);
                dsum += w0 + w1;
                float r0 = w0 * n0, r1 = w1 * n1;
                #pragma unroll
                for (int q = 0; q < 8; ++q) ac[q] += r0 * f0[q] + r1 * f1[q];
                // ---- rotate ----
                if (more) { ce0 = ne0; ce1 = ne1; cu0 = nu0; cu1 = nu1; }
                jb = jn;
            }
        }
        // ---- staged tail (deg < 64 only): clamped 4-edge passes ----
        for (; jb < dmax; jb += 4) {
            int j = jb + grp;
            bool vv = j < dmax;
            int ec = vv ? j : (dmax - 1);
            int2 e = sedge[wid][ec];
            int s = e.x;
            float nr = __int_as_float(e.y);
            H8 u; u.i4 = nh_in[(size_t)s * 16 + t];
            float f[8]; cvt8(u, f);
            float p = 0.f;
            #pragma unroll
            for (int q = 0; q < 8; ++q) p += f[q] * hd[q];
            p = red16(p);
            float w = vv ? __expf(beta * p) : 0.f;
            dsum += w;
            float r = w * nr;
            #pragma unroll
            for (int q = 0; q < 8; ++q) ac[q] += r * f[q];
        }
        // ---- rare far tail (deg > 64): direct loads ----
        for (jb = 64; jb < deg; jb += 4) {
            int j = jb + grp;
            bool vv = j < deg;
            int ec = vv ? j : (deg - 1);
            int s = csr_src[off + ec];
            float nr = nrm_in[s];
            H8 u; u.i4 = nh_in[(size_t)s * 16 + t];
            float f[8]; cvt8(u, f);
            float p = 0.f;
            #pragma unroll
            for (int q = 0; q < 8; ++q) p += f[q] * hd[q];
            p = red16(p);
            float w = vv ? __expf(beta * p) : 0.f;
            dsum += w;
            float r = w * nr;
            #pragma unroll
            for (int q = 0; q < 8; ++q) ac[q] += r * f[q];
        }

        // merge the 4 group partials (cross-row: shfl)
        #pragma unroll
        for (int o = 16; o < 64; o <<= 1) {
            dsum += __shfl_xor(dsum, o);
            #pragma unroll
            for (int k = 0; k < 8; ++k) ac[k] += __shfl_xor(ac[k], o);
        }
        float invd = 1.0f / dsum;
        #pragma unroll
        for (int k = 0; k < 8; ++k) ac[k] *= invd;
    }

    if (LAST) {
        // fused AvgPooling numerator: block = 4 nodes (sorted gid)
        __shared__ float spool[DIM];
        __shared__ int sg[4];
        int tid = threadIdx.x;
        int g = gid[node];
        if (lane == 0) sg[tid >> 6] = g;
        if (tid < DIM) spool[tid] = 0.f;
        __syncthreads();
        bool uni = (sg[0] == sg[1]) && (sg[1] == sg[2]) && (sg[2] == sg[3]);
        if (uni) {
            if (grp == 0) {
                #pragma unroll
                for (int k = 0; k < 8; ++k) atomicAdd(&spool[8 * t + k], ac[k]);
            }
            __syncthreads();
            if (tid < DIM) atomicAdd(&hgsum[(size_t)sg[0] * DIM + tid], spool[tid]);
        } else {
            if (grp == 0) {
                #pragma unroll
                for (int k = 0; k < 8; ++k)
                    atomicAdd(&hgsum[(size_t)g * DIM + 8 * t + k], ac[k]);
            }
        }
    } else {
        // normalize output row; write fp16 normalized table + norm scalar.
        // All 4 groups hold identical ac, so red16 IS the full ||row||^2.
        float ss = 0.f;
        #pragma unroll
        for (int k = 0; k < 8; ++k) ss += ac[k] * ac[k];
        ss = red16(ss);
        float norm = sqrtf(ss) + EPSN;
        float inv2 = 1.0f / norm;
        if (grp == 0) {
            H8 w;
            #pragma unroll
            for (int k = 0; k < 4; ++k)
                w.h2[k] = __floats2half2_rn(ac[2 * k] * inv2, ac[2 * k + 1] * inv2);
            nh_out[nrow16 + t] = w.i4;
        }
        if (lane == 0) nrm_out[node] = norm;
    }
}

// ---------------- readout ----------------

// one block (128 threads) per graph; counts via binary search on sorted gid
__global__ void k_cls(const float* __restrict__ hgsum, const int* __restrict__ gid,
                      const float* __restrict__ W, const float* __restrict__ b,
                      float* __restrict__ out) {
    int g = blockIdx.x;
    int c = threadIdx.x;
    __shared__ float invc_s;
    if (c == 0) {
        int lo = 0, hi = N_NODES;
        while (lo < hi) { int mid = (lo + hi) >> 1; if (gid[mid] < g) lo = mid + 1; else hi = mid; }
        int start = lo;
        lo = 0; hi = N_NODES;
        while (lo < hi) { int mid = (lo + hi) >> 1; if (gid[mid] < g + 1) lo = mid + 1; else hi = mid; }
        invc_s = 1.0f / fmaxf((float)(lo - start), 1.0f);
    }
    __syncthreads();
    if (c >= N_CLS) return;
    float acc = 0.f;
    #pragma unroll 8
    for (int d = 0; d < DIM; ++d) acc += hgsum[g * DIM + d] * W[d * N_CLS + c];
    out[g * N_CLS + c] = b[c] + acc * invc_s;
}

// ---------------- launch ----------------

extern "C" void kernel_launch(void* const* d_in, const int* in_sizes, int n_in,
                              void* d_out, int out_size, void* d_ws, size_t ws_size,
                              hipStream_t stream) {
    const float* h_in  = (const float*)d_in[0];
    const int*   src   = (const int*)  d_in[1];
    const int*   dst   = (const int*)  d_in[2];
    const int*   gid   = (const int*)  d_in[3];
    const float* betas = (const float*)d_in[4];
    const float* W     = (const float*)d_in[5];
    const float* bcls  = (const float*)d_in[6];
    float* out = (float*)d_out;

    char* p = (char*)d_ws;
    int4*  nh0     = (int4*)p;  p += (size_t)N_NODES * DIM * 2;   // 10.24 MB fp16 table
    int4*  nh1     = (int4*)p;  p += (size_t)N_NODES * DIM * 2;   // 10.24 MB fp16 table
    float* nrm0    = (float*)p; p += (size_t)N_NODES * 4;
    float* nrm1    = (float*)p; p += (size_t)N_NODES * 4;
    // --- contiguous zero-init region (memset) ---
    int*   counts  = (int*)p;   p += (size_t)N_NODES * 4;
    float* hgsum   = (float*)p; p += (size_t)N_GRAPHS * DIM * 4;
    // --------------------------------------------
    int*   offsets = (int*)p;   p += (size_t)(N_NODES + 4) * 4;   // N+1 used, padded
    int*   posw    = (int*)p;   p += (size_t)N_EDGES * 4;
    int*   csr_src = (int*)p;   p += (size_t)N_EDGES * 4;

    const size_t ZERO_BYTES = (size_t)(N_NODES + N_GRAPHS * DIM) * 4;

    // ---- CSR build + input norm (phases of one launch) ----
    hipMemsetAsync(counts, 0, ZERO_BYTES, stream);
    k_count_norm<<<EDGE_BLOCKS + NODE_BLOCKS, 256, 0, stream>>>(
        dst, counts, posw, h_in, nrm0, (__half2*)nh0);
    k_scan<<<1, SCAN_T, 0, stream>>>(counts, offsets);
    k_scatter<<<(N_EDGES + 255) / 256, 256, 0, stream>>>(src, dst, offsets, posw, csr_src);

    // ---- 3 AGNN layers on the normalized fp16 table ----
    k_fused<false><<<N_NODES / 4, 256, 0, stream>>>(nh0, nrm0, csr_src, offsets, betas, 0,
                                                    nh1, nrm1, nullptr, nullptr);
    k_fused<false><<<N_NODES / 4, 256, 0, stream>>>(nh1, nrm1, csr_src, offsets, betas, 1,
                                                    nh0, nrm0, nullptr, nullptr);
    k_fused<true><<<N_NODES / 4, 256, 0, stream>>>(nh0, nrm0, csr_src, offsets, betas, 2,
                                                   nullptr, nullptr, gid, hgsum);

    // ---- readout ----
    k_cls<<<N_GRAPHS, DIM, 0, stream>>>(hgsum, gid, W, bcls, out);
}

// Round 15
// 183.586 us; speedup vs baseline: 1.0581x; 1.0581x over previous
//
#include <hip/hip_runtime.h>
#include <hip/hip_fp16.h>
#include <math.h>

#define N_NODES 40000
#define N_EDGES 640000
#define DIM     128
#define N_GRAPHS 64
#define N_CLS   100
#define EPSN    1e-12f

#define EDGE_BLOCKS ((N_EDGES + 255) / 256)   // 2500
#define NODE_BLOCKS (N_NODES / 4)             // 10000

// ---------------- CSR build + input norm (fused, independent phases) --------

__global__ void k_count_norm(const int* __restrict__ dst, int* __restrict__ counts,
                             int* __restrict__ posw,
                             const float* __restrict__ h, float* __restrict__ nrm,
                             __half2* __restrict__ nh) {
    int b = blockIdx.x;
    if (b < EDGE_BLOCKS) {
        int e = b * 256 + threadIdx.x;
        if (e < N_EDGES) posw[e] = atomicAdd(&counts[dst[e]], 1);
    } else {
        int node = ((b - EDGE_BLOCKS) << 2) + (threadIdx.x >> 6);
        int lane = threadIdx.x & 63;
        const float2* r2 = (const float2*)(h + (size_t)node * DIM);
        float2 v = r2[lane];
        float ss = v.x * v.x + v.y * v.y;
        #pragma unroll
        for (int o = 32; o; o >>= 1) ss += __shfl_xor(ss, o);
        float norm = sqrtf(ss) + EPSN;
        float inv = 1.0f / norm;
        if (lane == 0) nrm[node] = norm;
        nh[(size_t)node * 64 + lane] = __floats2half2_rn(v.x * inv, v.y * inv);
    }
}

#define SCAN_T 1024
#define SCAN_V 40   // SCAN_T * SCAN_V >= N_NODES ; N_NODES/SCAN_V = 1000 exact
__global__ void k_scan(const int* __restrict__ counts, int* __restrict__ offsets) {
    __shared__ int lds[SCAN_T];
    int t = threadIdx.x;
    int base = t * SCAN_V;
    int tsum = 0;
    int c[SCAN_V];
    if (base < N_NODES) {
        const int4* c4 = (const int4*)(counts + base);   // 160B-aligned runs
        #pragma unroll
        for (int k = 0; k < SCAN_V / 4; ++k) {
            int4 v = c4[k];
            c[4 * k] = v.x; c[4 * k + 1] = v.y; c[4 * k + 2] = v.z; c[4 * k + 3] = v.w;
            tsum += v.x + v.y + v.z + v.w;
        }
    }
    lds[t] = tsum; __syncthreads();
    int x = tsum;
    for (int off = 1; off < SCAN_T; off <<= 1) {
        int y = (t >= off) ? lds[t - off] : 0;
        __syncthreads();
        x += y;
        lds[t] = x;
        __syncthreads();
    }
    int excl = x - tsum;
    if (base < N_NODES) {
        int run = excl;
        int4* o4 = (int4*)(offsets + base);
        #pragma unroll
        for (int k = 0; k < SCAN_V / 4; ++k) {
            int4 w;
            w.x = run;
            w.y = w.x + c[4 * k];
            w.z = w.y + c[4 * k + 1];
            w.w = w.z + c[4 * k + 2];
            run = w.w + c[4 * k + 3];
            o4[k] = w;
        }
    }
    if (t == (N_NODES / SCAN_V)) offsets[N_NODES] = excl;  // total = E
}

__global__ void k_scatter(const int* __restrict__ src, const int* __restrict__ dst,
                          const int* __restrict__ offsets, const int* __restrict__ posw,
                          int* __restrict__ csr_src) {
    int e = blockIdx.x * blockDim.x + threadIdx.x;
    if (e >= N_EDGES) return;
    csr_src[offsets[dst[e]] + posw[e]] = src[e];
}

// ---------------- fused AGNN layer ----------------

// One wave per node; 4 groups of 16 lanes; lane t owns features [8t..8t+7]
// (one int4 = 8 halves). Table holds NORMALIZED rows: score = beta*(nh_s.nh_d),
// aggregation weight = w*nrm[s] applied off the dot->exp critical path.
// Edge metadata (src idx + src norm) for the first min(deg,64) edges is STAGED
// IN LDS once per node, so the batch loop issues only the 2 row-gather vmem
// instrs per 8-edge batch. Per-wave LDS slot: no __syncthreads needed.
// 16-lane dot-reduce via DPP adds (VALU pipe, no LDS round-trip).
// Softmax needs no max subtraction: scores bounded in [-beta, beta].
// NOTE (R6/R9/R13 post-mortems): do NOT add register-funded ILP here —
// prefetch/pipelining raises VGPR 28->40+, drops occupancy, and loses.
union H8 { int4 i4; __half2 h2[4]; };

__device__ __forceinline__ void cvt8(const H8& u, float* f) {
    #pragma unroll
    for (int k = 0; k < 4; ++k) {
        float2 v = __half22float2(u.h2[k]);
        f[2 * k]     = v.x;
        f[2 * k + 1] = v.y;
    }
}

template <int CTRL>
__device__ __forceinline__ float dpp_add(float x) {
    int v = __builtin_amdgcn_update_dpp(0, __float_as_int(x), CTRL, 0xF, 0xF, true);
    return x + __int_as_float(v);
}

__device__ __forceinline__ float red16(float p) {
    p = dpp_add<0x140>(p);   // row_mirror
    p = dpp_add<0x141>(p);   // row_half_mirror
    p = dpp_add<0x4E>(p);    // quad_perm [2,3,0,1]  (xor 2)
    p = dpp_add<0xB1>(p);    // quad_perm [1,0,3,2]  (xor 1)
    return p;
}

template <bool LAST>
__global__ void k_fused(const int4* __restrict__ nh_in,      // fp16 normalized table
                        const float* __restrict__ nrm_in,    // |h|+eps per node
                        const int* __restrict__ csr_src,
                        const int* __restrict__ offsets,
                        const float* __restrict__ betas, int layer,
                        int4* __restrict__ nh_out,            // (if !LAST)
                        float* __restrict__ nrm_out,          // (if !LAST)
                        const int* __restrict__ gid,          // (if LAST)
                        float* __restrict__ hgsum) {          // (if LAST)
    int node = (blockIdx.x * blockDim.x + threadIdx.x) >> 6;  // grid covers exactly N_NODES
    int lane = threadIdx.x & 63;
    int wid  = threadIdx.x >> 6;   // wave slot in block (0..3)
    int grp = lane >> 4;   // 0..3
    int t   = lane & 15;   // feature sublane: owns features [8t..8t+7]

    __shared__ int2 sedge[4][64];  // per-wave slot: (src idx, src nrm bits)

    int off = offsets[node];
    int deg = offsets[node + 1] - off;

    size_t nrow16 = (size_t)node * 16;
    H8 selfu; selfu.i4 = nh_in[nrow16 + t];
    float hd[8]; cvt8(selfu, hd);
    float beta = betas[layer];

    float dsum = 0.f;
    float ac[8];
    #pragma unroll
    for (int k = 0; k < 8; ++k) ac[k] = 0.f;

    if (deg > 0) {
        int dmax = min(deg, 64);
        // ---- stage edge metadata for first dmax edges: 2 vmem instrs ----
        if (lane < dmax) {
            int idx = csr_src[off + lane];          // coalesced
            float nr = nrm_in[idx];                 // lane-parallel gather
            sedge[wid][lane] = make_int2(idx, __float_as_int(nr));
        }
        int jb = 0;
        // ---- full batches: 8 edges (2 per group); only 2 vmem instrs ----
        for (; jb + 8 <= dmax; jb += 8) {
            int2 e0 = sedge[wid][jb + grp];
            int2 e1 = sedge[wid][jb + 4 + grp];
            int s0 = e0.x, s1 = e1.x;
            float n0 = __int_as_float(e0.y), n1 = __int_as_float(e1.y);
            H8 u0, u1;
            u0.i4 = nh_in[(size_t)s0 * 16 + t];
            u1.i4 = nh_in[(size_t)s1 * 16 + t];
            float f0[8], f1[8];
            cvt8(u0, f0); cvt8(u1, f1);
            float p0 = 0.f, p1 = 0.f;
            #pragma unroll
            for (int q = 0; q < 8; ++q) { p0 += f0[q] * hd[q]; p1 += f1[q] * hd[q]; }
            p0 = red16(p0);
            p1 = red16(p1);
            float w0 = __expf(beta * p0), w1 = __expf(beta * p1);
            dsum += w0 + w1;
            float r0 = w0 * n0, r1 = w1 * n1;
            #pragma unroll
            for (int q = 0; q < 8; ++q) ac[q] += r0 * f0[q] + r1 * f1[q];
        }
        // ---- staged tail (deg < 64 only): clamped 4-edge passes ----
        for (; jb < dmax; jb += 4) {
            int j = jb + grp;
            bool vv = j < dmax;
            int ec = vv ? j : (dmax - 1);
            int2 e = sedge[wid][ec];
            int s = e.x;
            float nr = __int_as_float(e.y);
            H8 u; u.i4 = nh_in[(size_t)s * 16 + t];
            float f[8]; cvt8(u, f);
            float p = 0.f;
            #pragma unroll
            for (int q = 0; q < 8; ++q) p += f[q] * hd[q];
            p = red16(p);
            float w = vv ? __expf(beta * p) : 0.f;
            dsum += w;
            float r = w * nr;
            #pragma unroll
            for (int q = 0; q < 8; ++q) ac[q] += r * f[q];
        }
        // ---- rare far tail (deg > 64): direct loads ----
        for (jb = 64; jb < deg; jb += 4) {
            int j = jb + grp;
            bool vv = j < deg;
            int ec = vv ? j : (deg - 1);
            int s = csr_src[off + ec];
            float nr = nrm_in[s];
            H8 u; u.i4 = nh_in[(size_t)s * 16 + t];
            float f[8]; cvt8(u, f);
            float p = 0.f;
            #pragma unroll
            for (int q = 0; q < 8; ++q) p += f[q] * hd[q];
            p = red16(p);
            float w = vv ? __expf(beta * p) : 0.f;
            dsum += w;
            float r = w * nr;
            #pragma unroll
            for (int q = 0; q < 8; ++q) ac[q] += r * f[q];
        }

        // merge the 4 group partials (cross-row: shfl)
        #pragma unroll
        for (int o = 16; o < 64; o <<= 1) {
            dsum += __shfl_xor(dsum, o);
            #pragma unroll
            for (int k = 0; k < 8; ++k) ac[k] += __shfl_xor(ac[k], o);
        }
        float invd = 1.0f / dsum;
        #pragma unroll
        for (int k = 0; k < 8; ++k) ac[k] *= invd;
    }

    if (LAST) {
        // fused AvgPooling numerator: block = 4 nodes (sorted gid)
        __shared__ float spool[DIM];
        __shared__ int sg[4];
        int tid = threadIdx.x;
        int g = gid[node];
        if (lane == 0) sg[tid >> 6] = g;
        if (tid < DIM) spool[tid] = 0.f;
        __syncthreads();
        bool uni = (sg[0] == sg[1]) && (sg[1] == sg[2]) && (sg[2] == sg[3]);
        if (uni) {
            if (grp == 0) {
                #pragma unroll
                for (int k = 0; k < 8; ++k) atomicAdd(&spool[8 * t + k], ac[k]);
            }
            __syncthreads();
            if (tid < DIM) atomicAdd(&hgsum[(size_t)sg[0] * DIM + tid], spool[tid]);
        } else {
            if (grp == 0) {
                #pragma unroll
                for (int k = 0; k < 8; ++k)
                    atomicAdd(&hgsum[(size_t)g * DIM + 8 * t + k], ac[k]);
            }
        }
    } else {
        // normalize output row; write fp16 normalized table + norm scalar.
        // All 4 groups hold identical ac, so red16 IS the full ||row||^2.
        float ss = 0.f;
        #pragma unroll
        for (int k = 0; k < 8; ++k) ss += ac[k] * ac[k];
        ss = red16(ss);
        float norm = sqrtf(ss) + EPSN;
        float inv2 = 1.0f / norm;
        if (grp == 0) {
            H8 w;
            #pragma unroll
            for (int k = 0; k < 4; ++k)
                w.h2[k] = __floats2half2_rn(ac[2 * k] * inv2, ac[2 * k + 1] * inv2);
            nh_out[nrow16 + t] = w.i4;
        }
        if (lane == 0) nrm_out[node] = norm;
    }
}

// ---------------- readout ----------------

// one block (128 threads) per graph; counts via binary search on sorted gid
__global__ void k_cls(const float* __restrict__ hgsum, const int* __restrict__ gid,
                      const float* __restrict__ W, const float* __restrict__ b,
                      float* __restrict__ out) {
    int g = blockIdx.x;
    int c = threadIdx.x;
    __shared__ float invc_s;
    if (c == 0) {
        int lo = 0, hi = N_NODES;
        while (lo < hi) { int mid = (lo + hi) >> 1; if (gid[mid] < g) lo = mid + 1; else hi = mid; }
        int start = lo;
        lo = 0; hi = N_NODES;
        while (lo < hi) { int mid = (lo + hi) >> 1; if (gid[mid] < g + 1) lo = mid + 1; else hi = mid; }
        invc_s = 1.0f / fmaxf((float)(lo - start), 1.0f);
    }
    __syncthreads();
    if (c >= N_CLS) return;
    float acc = 0.f;
    #pragma unroll 8
    for (int d = 0; d < DIM; ++d) acc += hgsum[g * DIM + d] * W[d * N_CLS + c];
    out[g * N_CLS + c] = b[c] + acc * invc_s;
}

// ---------------- launch ----------------

extern "C" void kernel_launch(void* const* d_in, const int* in_sizes, int n_in,
                              void* d_out, int out_size, void* d_ws, size_t ws_size,
                              hipStream_t stream) {
    const float* h_in  = (const float*)d_in[0];
    const int*   src   = (const int*)  d_in[1];
    const int*   dst   = (const int*)  d_in[2];
    const int*   gid   = (const int*)  d_in[3];
    const float* betas = (const float*)d_in[4];
    const float* W     = (const float*)d_in[5];
    const float* bcls  = (const float*)d_in[6];
    float* out = (float*)d_out;

    char* p = (char*)d_ws;
    int4*  nh0     = (int4*)p;  p += (size_t)N_NODES * DIM * 2;   // 10.24 MB fp16 table
    int4*  nh1     = (int4*)p;  p += (size_t)N_NODES * DIM * 2;   // 10.24 MB fp16 table
    float* nrm0    = (float*)p; p += (size_t)N_NODES * 4;
    float* nrm1    = (float*)p; p += (size_t)N_NODES * 4;
    // --- contiguous zero-init region (memset) ---
    int*   counts  = (int*)p;   p += (size_t)N_NODES * 4;
    float* hgsum   = (float*)p; p += (size_t)N_GRAPHS * DIM * 4;
    // --------------------------------------------
    int*   offsets = (int*)p;   p += (size_t)(N_NODES + 4) * 4;   // N+1 used, padded
    int*   posw    = (int*)p;   p += (size_t)N_EDGES * 4;
    int*   csr_src = (int*)p;   p += (size_t)N_EDGES * 4;

    const size_t ZERO_BYTES = (size_t)(N_NODES + N_GRAPHS * DIM) * 4;

    // ---- CSR build + input norm (phases of one launch) ----
    hipMemsetAsync(counts, 0, ZERO_BYTES, stream);
    k_count_norm<<<EDGE_BLOCKS + NODE_BLOCKS, 256, 0, stream>>>(
        dst, counts, posw, h_in, nrm0, (__half2*)nh0);
    k_scan<<<1, SCAN_T, 0, stream>>>(counts, offsets);
    k_scatter<<<(N_EDGES + 255) / 256, 256, 0, stream>>>(src, dst, offsets, posw, csr_src);

    // ---- 3 AGNN layers on the normalized fp16 table ----
    k_fused<false><<<N_NODES / 4, 256, 0, stream>>>(nh0, nrm0, csr_src, offsets, betas, 0,
                                                    nh1, nrm1, nullptr, nullptr);
    k_fused<false><<<N_NODES / 4, 256, 0, stream>>>(nh1, nrm1, csr_src, offsets, betas, 1,
                                                    nh0, nrm0, nullptr, nullptr);
    k_fused<true><<<N_NODES / 4, 256, 0, stream>>>(nh0, nrm0, csr_src, offsets, betas, 2,
                                                   nullptr, nullptr, gid, hgsum);

    // ---- readout ----
    k_cls<<<N_GRAPHS, DIM, 0, stream>>>(hgsum, gid, W, bcls, out);
}